// Round 1
// baseline (209.653 us; speedup 1.0000x reference)
//
#include <hip/hip_runtime.h>

#define VOCAB 32000
#define DIM   128
#define BB    16
#define MM    4096
#define SS    4
#define NCH   64            // chunks of M per batch for o_k partials
#define MCH   (MM / NCH)    // 64 m's per block

// ---------------- init: u = enc_query ----------------
__global__ __launch_bounds__(256) void k_init(const float* __restrict__ q,
                                              float* __restrict__ u) {
    int i = blockIdx.x * 256 + threadIdx.x;   // grid covers exactly B*DIM
    u[i] = q[i];
}

// ---------------- logits: lg[b,m] = dot(sum_s C[hop][story[b,m,s]], u[b]) ----
// one wave per (b,m); lane covers 2 dims (float2), 64 lanes * 8B = full 512B row
__global__ __launch_bounds__(256) void k_logits(const int* __restrict__ story,
                                                const float* __restrict__ C,
                                                const float* __restrict__ u,
                                                float* __restrict__ lg,
                                                int hop) {
    int gid  = blockIdx.x * 4 + (threadIdx.x >> 6);  // = b*MM + m, grid exact
    int lane = threadIdx.x & 63;
    int b    = gid >> 12;                            // / MM (4096)

    const int* st = story + (size_t)gid * SS;
    int i0 = st[0], i1 = st[1], i2 = st[2], i3 = st[3];

    const float* Ch = C + (size_t)hop * VOCAB * DIM;
    float2 v0 = ((const float2*)(Ch + (size_t)i0 * DIM))[lane];
    float2 v1 = ((const float2*)(Ch + (size_t)i1 * DIM))[lane];
    float2 v2 = ((const float2*)(Ch + (size_t)i2 * DIM))[lane];
    float2 v3 = ((const float2*)(Ch + (size_t)i3 * DIM))[lane];
    float2 uu = ((const float2*)(u + (size_t)b * DIM))[lane];

    float ax = (v0.x + v1.x) + (v2.x + v3.x);
    float ay = (v0.y + v1.y) + (v2.y + v3.y);
    float p  = ax * uu.x + ay * uu.y;

    #pragma unroll
    for (int off = 32; off; off >>= 1) p += __shfl_down(p, off, 64);
    if (lane == 0) lg[gid] = p;
}

// ---------------- softmax stats: row max + sum of exp per batch --------------
__global__ __launch_bounds__(256) void k_stats(const float* __restrict__ lg,
                                               float* __restrict__ rmax,
                                               float* __restrict__ rsum) {
    int b = blockIdx.x;
    int t = threadIdx.x;
    const float* L = lg + (size_t)b * MM;

    float vals[MM / 256];
    float mx = -1e30f;
    #pragma unroll
    for (int i = 0; i < MM / 256; i++) {
        vals[i] = L[t + i * 256];
        mx = fmaxf(mx, vals[i]);
    }
    #pragma unroll
    for (int off = 32; off; off >>= 1) mx = fmaxf(mx, __shfl_down(mx, off, 64));

    __shared__ float sm[4];
    __shared__ float ss[4];
    int wave = t >> 6, lane = t & 63;
    if (lane == 0) sm[wave] = mx;
    __syncthreads();
    float bm = fmaxf(fmaxf(sm[0], sm[1]), fmaxf(sm[2], sm[3]));

    float sum = 0.f;
    #pragma unroll
    for (int i = 0; i < MM / 256; i++) sum += __expf(vals[i] - bm);
    #pragma unroll
    for (int off = 32; off; off >>= 1) sum += __shfl_down(sum, off, 64);
    if (lane == 0) ss[wave] = sum;
    __syncthreads();
    if (t == 0) {
        rmax[b] = bm;
        rsum[b] = ss[0] + ss[1] + ss[2] + ss[3];
    }
}

// ---------------- o_k partials: partial[b,ch,d] = sum_{m in ch} p * msC[b,m,d]
// block = 128 threads (one per d); each block handles MCH m's of one batch
__global__ __launch_bounds__(128) void k_ok(const int* __restrict__ story,
                                            const float* __restrict__ C,
                                            const float* __restrict__ lg,
                                            const float* __restrict__ rmax,
                                            const float* __restrict__ rsum,
                                            float* __restrict__ partial,
                                            int hop) {
    int ch = blockIdx.x;
    int b  = blockIdx.y;
    int d  = threadIdx.x;

    const float* Cn  = C + (size_t)(hop + 1) * VOCAB * DIM;
    float mx  = rmax[b];
    float inv = 1.f / rsum[b];

    int m0 = ch * MCH;
    const int*   st = story + ((size_t)b * MM + m0) * SS;
    const float* L  = lg + (size_t)b * MM + m0;

    float acc = 0.f;
    for (int j = 0; j < MCH; j++) {
        float p = __expf(L[j] - mx);
        int i0 = st[0], i1 = st[1], i2 = st[2], i3 = st[3];
        st += SS;
        float v = Cn[(size_t)i0 * DIM + d] + Cn[(size_t)i1 * DIM + d] +
                  Cn[(size_t)i2 * DIM + d] + Cn[(size_t)i3 * DIM + d];
        acc += p * v;
    }
    partial[((size_t)b * NCH + ch) * DIM + d] = acc * inv;
}

// ---------------- u update: u[b,d] += sum_ch partial[b,ch,d] -----------------
__global__ __launch_bounds__(128) void k_update(float* __restrict__ u,
                                                const float* __restrict__ partial,
                                                float* __restrict__ u1_out,
                                                int write_u1) {
    int b = blockIdx.x;
    int d = threadIdx.x;
    float acc = u[(size_t)b * DIM + d];
    for (int ch = 0; ch < NCH; ch++)
        acc += partial[((size_t)b * NCH + ch) * DIM + d];
    u[(size_t)b * DIM + d] = acc;
    if (write_u1) u1_out[(size_t)b * DIM + d] = acc;
}

extern "C" void kernel_launch(void* const* d_in, const int* in_sizes, int n_in,
                              void* d_out, int out_size, void* d_ws, size_t ws_size,
                              hipStream_t stream) {
    const int*   story = (const int*)d_in[0];
    const float* q     = (const float*)d_in[1];
    const float* C     = (const float*)d_in[2];

    float* out = (float*)d_out;           // [B*M logits][B*D u1]
    float* ws  = (float*)d_ws;

    // ws layout (floats)
    float* u       = ws;                          // B*DIM        = 2048
    float* lg      = ws + 2048;                   // B*MM         = 65536
    float* rmax    = ws + 2048 + 65536;           // B            = 16
    float* rsum    = rmax + BB;                   // B            = 16
    float* partial = rsum + BB;                   // B*NCH*DIM    = 131072
    // total ~ 795 KB << ws

    float* out_u1 = out + BB * MM;

    k_init<<<(BB * DIM) / 256, 256, 0, stream>>>(q, u);

    for (int hop = 0; hop < 3; hop++) {
        float* lgp = (hop == 2) ? out : lg;
        k_logits<<<(BB * MM) / 4, 256, 0, stream>>>(story, C, u, lgp, hop);
        k_stats<<<BB, 256, 0, stream>>>(lgp, rmax, rsum);
        k_ok<<<dim3(NCH, BB), 128, 0, stream>>>(story, C, lgp, rmax, rsum, partial, hop);
        k_update<<<BB, 128, 0, stream>>>(u, partial, out_u1, hop == 0 ? 1 : 0);
    }
}